// Round 2
// baseline (1175.767 us; speedup 1.0000x reference)
//
#include <hip/hip_runtime.h>

// Wide & Deep forward, MI355X.
// K1: gather embeddings + 2-layer MLP -> h2 (4096x128) bf16 into d_ws.
// K2: fused head, one block per 16 output columns (j), full batch looped
//     inside the block so every gathered w_head cache line is fetched once.

#define BATCH    4096
#define NITEMS   10000
#define HEADCOLS 10128   // 10000 one-hot + 128 dense
#define DENSEOFF 10000

typedef __attribute__((ext_vector_type(8))) short short8;
typedef __attribute__((ext_vector_type(4))) short short4v;
typedef __attribute__((ext_vector_type(4))) float floatx4;

__device__ inline unsigned short f2bf(float f) {
    unsigned u = __builtin_bit_cast(unsigned, f);
    unsigned r = (u + 0x7FFFu + ((u >> 16) & 1u)) >> 16;
    return (unsigned short)r;
}

// ---------------- K1: embeddings + MLP -> h2 (bf16) ----------------
// 256 blocks x 256 threads; each block handles 16 batch rows.
__global__ __launch_bounds__(256) void k1_mlp(
    const int* __restrict__ inter,
    const float* __restrict__ U, const float* __restrict__ I,
    const float* __restrict__ w1, const float* __restrict__ b1,
    const float* __restrict__ w2, const float* __restrict__ b2,
    unsigned short* __restrict__ h2b)
{
    __shared__ float e_lds[16 * 64];
    __shared__ float h1_lds[16 * 128];
    const int t  = threadIdx.x;
    const int b0 = blockIdx.x * 16;

    // stage concat(user_emb, item_emb): 16 rows x 64
    for (int idx = t; idx < 16 * 64; idx += 256) {
        int b = idx >> 6, d = idx & 63;
        int u  = inter[2 * (b0 + b)];
        int it = inter[2 * (b0 + b) + 1];
        e_lds[idx] = (d < 32) ? U[(long)u * 32 + d] : I[(long)it * 32 + (d - 32)];
    }
    __syncthreads();

    // layer 1: h1[b][i] = relu(w1[i,:] . e[b,:] + b1[i])
    {
        const int i = t & 127;
        const int g = (t >> 7) * 8;     // 2 groups x 8 rows
        float acc[8];
        #pragma unroll
        for (int b = 0; b < 8; b++) acc[b] = b1[i];
        for (int d = 0; d < 64; d += 4) {
            float4 w = *(const float4*)&w1[i * 64 + d];
            #pragma unroll
            for (int b = 0; b < 8; b++) {
                const float* e = &e_lds[(g + b) * 64 + d];   // LDS broadcast
                acc[b] += w.x * e[0] + w.y * e[1] + w.z * e[2] + w.w * e[3];
            }
        }
        #pragma unroll
        for (int b = 0; b < 8; b++) h1_lds[(g + b) * 128 + i] = fmaxf(acc[b], 0.f);
    }
    __syncthreads();

    // layer 2: h2[b][o] = relu(w2[o,:] . h1[b,:] + b2[o]) -> bf16
    {
        const int o = t & 127;
        const int g = (t >> 7) * 8;
        float acc[8];
        #pragma unroll
        for (int b = 0; b < 8; b++) acc[b] = b2[o];
        for (int k = 0; k < 128; k += 4) {
            float4 w = *(const float4*)&w2[o * 128 + k];
            #pragma unroll
            for (int b = 0; b < 8; b++) {
                const float* h = &h1_lds[(g + b) * 128 + k];  // LDS broadcast
                acc[b] += w.x * h[0] + w.y * h[1] + w.z * h[2] + w.w * h[3];
            }
        }
        #pragma unroll
        for (int b = 0; b < 8; b++)
            h2b[(long)(b0 + g + b) * 128 + o] = f2bf(fmaxf(acc[b], 0.f));
    }
}

// ---------------- K2: fused head ----------------
// 625 blocks (10000/16 exact), 256 threads (4 waves).
// Block owns j in [jbase, jbase+16); loops over batch in chunks of 256
// (64 rows per wave). 16x16x32 bf16 MFMA, K=128 unrolled (4 steps).
// A-frags from global h2 (L2-resident); B-frags hoisted to registers.
#define BSTR 136   // B_lds row stride in bf16 elems (128 + 8 pad)

__global__ __launch_bounds__(256) void k2_head(
    const unsigned short* __restrict__ h2b,
    const float* __restrict__ w_head, const float* __restrict__ b_head,
    const int* __restrict__ inter, float* __restrict__ out)
{
    __shared__ short B_lds[16 * BSTR];

    const int t     = threadIdx.x;
    const int jbase = blockIdx.x * 16;

    // stage B: dense cols of w_head (16 j-rows x 128), f32 -> bf16
    for (int idx = t; idx < 16 * 32; idx += 256) {
        int r = idx >> 5, s = idx & 31;
        float4 w = *(const float4*)&w_head[(long)(jbase + r) * HEADCOLS + DENSEOFF + s * 4];
        short4v o4;
        o4[0] = (short)f2bf(w.x); o4[1] = (short)f2bf(w.y);
        o4[2] = (short)f2bf(w.z); o4[3] = (short)f2bf(w.w);
        *(short4v*)&B_lds[r * BSTR + s * 4] = o4;
    }
    __syncthreads();

    const int lane = t & 63, wave = t >> 6;
    const int col  = lane & 15, quad = lane >> 4;
    const int j    = jbase + col;             // this lane's output column
    const float bias    = b_head[j];
    const long  wrowoff = (long)j * HEADCOLS; // gather row for the wide term

    // B fragments (invariant over batch): B[n=col][k=ks*32+quad*8 ..+7]
    short8 bfrag[4];
    #pragma unroll
    for (int ks = 0; ks < 4; ks++)
        bfrag[ks] = *(const short8*)&B_lds[col * BSTR + ks * 32 + quad * 8];

    for (int chunk = 0; chunk < BATCH; chunk += 256) {
        const int wb = chunk + wave * 64;     // this wave's 64 batch rows

        // issue the 16 wide-term gathers early (HBM latency hidden by MFMA)
        float wide[4][4];
        #pragma unroll
        for (int bi = 0; bi < 4; bi++) {
            #pragma unroll
            for (int r = 0; r < 4; r++) {
                int b  = wb + bi * 16 + quad * 4 + r;
                int it = inter[2 * b + 1];
                wide[bi][r] = w_head[wrowoff + it];
            }
        }

        floatx4 acc[4];
        #pragma unroll
        for (int bi = 0; bi < 4; bi++)
            #pragma unroll
            for (int r = 0; r < 4; r++) acc[bi][r] = 0.f;

        // K = 128 = 4 x 32; A[m=col][k] straight from global h2
        #pragma unroll
        for (int ks = 0; ks < 4; ks++) {
            short8 a[4];
            #pragma unroll
            for (int bi = 0; bi < 4; bi++)
                a[bi] = *(const short8*)&h2b[(long)(wb + bi * 16 + col) * 128 + ks * 32 + quad * 8];
            #pragma unroll
            for (int bi = 0; bi < 4; bi++)
                acc[bi] = __builtin_amdgcn_mfma_f32_16x16x32_bf16(a[bi], bfrag[ks], acc[bi], 0, 0, 0);
        }

        // epilogue: C/D layout col=lane&15 (j), row=quad*4+r (b)
        #pragma unroll
        for (int bi = 0; bi < 4; bi++) {
            #pragma unroll
            for (int r = 0; r < 4; r++) {
                int b = wb + bi * 16 + quad * 4 + r;
                float x = acc[bi][r] + bias + wide[bi][r];
                out[(long)b * NITEMS + j] = 1.f / (1.f + __expf(-x));
            }
        }
    }
}

extern "C" void kernel_launch(void* const* d_in, const int* in_sizes, int n_in,
                              void* d_out, int out_size, void* d_ws, size_t ws_size,
                              hipStream_t stream) {
    const int*   inter = (const int*)d_in[0];
    const float* U     = (const float*)d_in[1];
    const float* I     = (const float*)d_in[2];
    const float* w1    = (const float*)d_in[3];
    const float* b1    = (const float*)d_in[4];
    const float* w2    = (const float*)d_in[5];
    const float* b2    = (const float*)d_in[6];
    const float* wh    = (const float*)d_in[7];
    const float* bh    = (const float*)d_in[8];
    float* out = (float*)d_out;
    unsigned short* h2b = (unsigned short*)d_ws;   // 4096*128 bf16 = 1 MB

    k1_mlp<<<256, 256, 0, stream>>>(inter, U, I, w1, b1, w2, b2, h2b);
    k2_head<<<625, 256, 0, stream>>>(h2b, wh, bh, inter, out);
}